// Round 3
// baseline (3146.038 us; speedup 1.0000x reference)
//
#include <hip/hip_runtime.h>
#include <math.h>

#define NB 16
#define T  2048
#define D  512
#define BD 64
#define BT (NB*T)  // 32768

// workspace layout (float offsets)
#define OFF_K   0
#define OFF_V   (BT*BD)
#define OFF_Q   (2*BT*BD)
#define OFF_ETA (3*BT*BD)
#define OFF_H   (3*BT*BD + BT)
// total floats = 4*BT*BD + BT = 8,421,376  (~33.7 MB)

// ---------------- DPP full-wave sum, result broadcast to all lanes ----------
__device__ __forceinline__ float wave_allsum(float x) {
  x += __int_as_float(__builtin_amdgcn_update_dpp(
      0, __float_as_int(x), 0x111, 0xf, 0xf, true));   // row_shr:1
  x += __int_as_float(__builtin_amdgcn_update_dpp(
      0, __float_as_int(x), 0x112, 0xf, 0xf, true));   // row_shr:2
  x += __int_as_float(__builtin_amdgcn_update_dpp(
      0, __float_as_int(x), 0x114, 0xf, 0xf, true));   // row_shr:4
  x += __int_as_float(__builtin_amdgcn_update_dpp(
      0, __float_as_int(x), 0x118, 0xf, 0xf, true));   // row_shr:8
  x += __int_as_float(__builtin_amdgcn_update_dpp(
      0, __float_as_int(x), 0x142, 0xa, 0xf, false));  // row_bcast:15 -> rows 1,3
  x += __int_as_float(__builtin_amdgcn_update_dpp(
      0, __float_as_int(x), 0x143, 0xc, 0xf, false));  // row_bcast:31 -> rows 2,3
  return __int_as_float(__builtin_amdgcn_readlane(__float_as_int(x), 63));
}

// ---------------- projection: K,V,Q = x @ W{k,v,q} + b ----------------
__device__ __forceinline__ void do_proj(const float* __restrict__ W,
                                        const float* __restrict__ bias,
                                        float* __restrict__ Out,
                                        const float* xs, int col, int rg,
                                        size_t row0) {
  float a0 = 0.f, a1 = 0.f, a2 = 0.f, a3 = 0.f;
  for (int d = 0; d < D; d += 4) {
    float w0 = W[(d + 0) * BD + col];
    float w1 = W[(d + 1) * BD + col];
    float w2 = W[(d + 2) * BD + col];
    float w3 = W[(d + 3) * BD + col];
    const float* xb = xs + (rg * 4) * D + d;
    float4 x0 = *(const float4*)(xb);
    float4 x1 = *(const float4*)(xb + D);
    float4 x2 = *(const float4*)(xb + 2 * D);
    float4 x3 = *(const float4*)(xb + 3 * D);
    a0 += x0.x * w0 + x0.y * w1 + x0.z * w2 + x0.w * w3;
    a1 += x1.x * w0 + x1.y * w1 + x1.z * w2 + x1.w * w3;
    a2 += x2.x * w0 + x2.y * w1 + x2.z * w2 + x2.w * w3;
    a3 += x3.x * w0 + x3.y * w1 + x3.z * w2 + x3.w * w3;
  }
  float bb = bias[col];
  Out[(row0 + rg * 4 + 0) * BD + col] = a0 + bb;
  Out[(row0 + rg * 4 + 1) * BD + col] = a1 + bb;
  Out[(row0 + rg * 4 + 2) * BD + col] = a2 + bb;
  Out[(row0 + rg * 4 + 3) * BD + col] = a3 + bb;
}

__global__ __launch_bounds__(256) void proj_kernel(
    const float* __restrict__ x,
    const float* __restrict__ Wk, const float* __restrict__ bk,
    const float* __restrict__ Wv, const float* __restrict__ bv,
    const float* __restrict__ Wq, const float* __restrict__ bq,
    float* __restrict__ Kout, float* __restrict__ Vout,
    float* __restrict__ Qout) {
  __shared__ __align__(16) float xs[16 * D];  // 32 KB
  const int tid = threadIdx.x;
  const size_t row0 = (size_t)blockIdx.x * 16;
  const float4* xg = (const float4*)(x + row0 * D);
  float4* xs4 = (float4*)xs;
#pragma unroll
  for (int i = 0; i < 8; i++) xs4[i * 256 + tid] = xg[i * 256 + tid];
  __syncthreads();
  const int col = tid & 63;
  const int rg = tid >> 6;  // 4 row-groups of 4 rows
  do_proj(Wk, bk, Kout, xs, col, rg, row0);
  do_proj(Wv, bv, Vout, xs, col, rg, row0);
  do_proj(Wq, bq, Qout, xs, col, rg, row0);
}

// ---------------- eta = sigmoid(x . lr_w + lr_b) ----------------
__global__ __launch_bounds__(256) void eta_kernel(const float* __restrict__ x,
                                                  const float* __restrict__ lr_w,
                                                  const float* __restrict__ lr_b,
                                                  float* __restrict__ eta) {
  const int tid = threadIdx.x;
  const int lane = tid & 63;
  const int wv = tid >> 6;
  const size_t r = (size_t)blockIdx.x * 4 + wv;  // one wave per row
  const float* xr = x + r * D + lane * 8;
  float4 a = *(const float4*)xr;
  float4 b = *(const float4*)(xr + 4);
  const float* lw = lr_w + lane * 8;
  float4 la = *(const float4*)lw;
  float4 lb = *(const float4*)(lw + 4);
  float p = a.x * la.x + a.y * la.y + a.z * la.z + a.w * la.w +
            b.x * lb.x + b.y * lb.y + b.z * lb.z + b.w * lb.w;
#pragma unroll
  for (int m = 32; m > 0; m >>= 1) p += __shfl_xor(p, m, 64);
  if (lane == 0) eta[r] = 1.0f / (1.0f + expf(-(p + lr_b[0])));
}

// ---------------- sequential TTT scan: one wave per batch element ----------
// Single wave per block: no barriers; amdgpu_waves_per_eu(1) lifts the VGPR
// cap (we run exactly 1 wave/CU) so the whole step's k/q broadcast vectors
// live in registers and LDS reads batch instead of serializing.
__global__ __launch_bounds__(64) __attribute__((amdgpu_waves_per_eu(1)))
void ttt_seq_kernel(
    const float* __restrict__ Kin, const float* __restrict__ Vin,
    const float* __restrict__ Qin, const float* __restrict__ eta_in,
    const float* __restrict__ W0, const float* __restrict__ ln_g,
    const float* __restrict__ ln_b, float* __restrict__ Hout) {
  __shared__ __align__(16) float4 lk4[2][16];
  __shared__ __align__(16) float4 lq4[2][16];
  const int lane = threadIdx.x;
  const int b = blockIdx.x;

  // lane o holds W row o in registers
  float w[64];
  const float4* w04 = (const float4*)(W0 + (size_t)lane * BD);
#pragma unroll
  for (int i = 0; i < 16; i++) {
    float4 t = w04[i];
    w[4 * i] = t.x; w[4 * i + 1] = t.y; w[4 * i + 2] = t.z; w[4 * i + 3] = t.w;
  }
  const float g = ln_g[lane];
  const float bet = ln_b[lane];
  const float a = g * g;
  const float A2 = wave_allsum(a);  // sum of g^2 (constant over the scan)

  size_t base = (size_t)b * T * BD;
  size_t ebase = (size_t)b * T;
  // preload t=0, start prefetch of t=1
  float k = Kin[base + lane];
  float v = Vin[base + lane];
  float q = Qin[base + lane];
  float eta = eta_in[ebase];
  float kn = Kin[base + BD + lane];
  float vn = Vin[base + BD + lane];
  float qn = Qin[base + BD + lane];
  float etan = eta_in[ebase + 1];
  // stage t=0 broadcast buffers
  ((float*)lk4[0])[lane] = k;
  ((float*)lq4[0])[lane] = q;

  for (int t = 0; t < T; t++) {
    const int buf = t & 1;
    const int nbuf = buf ^ 1;
    // prefetch t+2 (off-end reads stay inside d_ws: K->V->Q->ETA->H)
    float kn2 = Kin[base + 2 * BD + lane];
    float vn2 = Vin[base + 2 * BD + lane];
    float qn2 = Qin[base + 2 * BD + lane];
    float etan2 = eta_in[ebase + t + 2];

    // pull the whole broadcast k/q vectors into registers (32 x b128)
    float4 kk[16], qq[16];
#pragma unroll
    for (int i = 0; i < 16; i++) { kk[i] = lk4[buf][i]; qq[i] = lq4[buf][i]; }

    // u = k @ W^T  and  p = q @ W_old^T   (lane o computes row o)
    float u0 = 0.f, u1 = 0.f, u2a = 0.f, u3 = 0.f;
    float p0 = 0.f, p1 = 0.f, p2 = 0.f, p3 = 0.f;
#pragma unroll
    for (int i = 0; i < 16; i++) {
      u0 += kk[i].x * w[4 * i];     p0 += qq[i].x * w[4 * i];
      u1 += kk[i].y * w[4 * i + 1]; p1 += qq[i].y * w[4 * i + 1];
      u2a += kk[i].z * w[4 * i + 2]; p2 += qq[i].z * w[4 * i + 2];
      u3 += kk[i].w * w[4 * i + 3]; p3 += qq[i].w * w[4 * i + 3];
    }
    float u = (u0 + u1) + (u2a + u3);
    float p = (p0 + p1) + (p2 + p3);

    // ---- single merged reduction phase (7 interleaved DPP sums) ----
    // c = g(k + beta - v);  dxh = (2/64)(c + a*xh)  with a = g^2
    float c = g * (k + bet - v);
    float Su   = wave_allsum(u);
    float Suu  = wave_allsum(u * u);
    float Sau  = wave_allsum(a * u);
    float Sauu = wave_allsum(a * u * u);
    float Sc   = wave_allsum(c);
    float Scu  = wave_allsum(c * u);
    float Qk   = wave_allsum(q * k);

    float mu = Su * (1.0f / 64);
    float var = Suu * (1.0f / 64) - mu * mu;
    float rstd = rsqrtf(var + 1e-6f);
    float xh = (u - mu) * rstd;
    // s1 = sum(dxh), s2 = sum(dxh*xh) via expansion:
    float Axh   = rstd * (Sau - mu * A2);                         // sum a*xh
    float Scxh  = rstd * (Scu - mu * Sc);                         // sum c*xh
    float Saxh2 = rstd * rstd * (Sauu - 2.0f * mu * Sau + mu * mu * A2);
    float s1 = (2.0f / 64) * (Sc + Axh);
    float s2 = (2.0f / 64) * (Scxh + Saxh2);
    float dxh = (2.0f / 64) * (c + a * xh);
    float dldu = rstd * (dxh - s1 * (1.0f / 64) - xh * (s2 * (1.0f / 64)));
    float coef = -eta * dldu;  // W_new row o = w + coef*k

    // u2 = q @ W_new^T = p + coef * (q.k)   (rank-1 identity)
    float u2 = p + coef * Qk;

    // W update reuses the register copies of k (no second LDS pass)
#pragma unroll
    for (int i = 0; i < 16; i++) {
      w[4 * i]     += coef * kk[i].x;
      w[4 * i + 1] += coef * kk[i].y;
      w[4 * i + 2] += coef * kk[i].z;
      w[4 * i + 3] += coef * kk[i].w;
    }

    // ---- phase 2: LN stats of u2 ----
    float Su2  = wave_allsum(u2);
    float Suu2 = wave_allsum(u2 * u2);
    float mu2 = Su2 * (1.0f / 64);
    float rstd2 = rsqrtf(Suu2 * (1.0f / 64) - mu2 * mu2 + 1e-6f);
    float h = q + (u2 - mu2) * rstd2 * g + bet;
    Hout[base + lane] = h;

    // stage t+1 broadcast buffers late (loads have landed; next step's
    // LDS reads then don't wait on a fresh write)
    ((float*)lk4[nbuf])[lane] = kn;
    ((float*)lq4[nbuf])[lane] = qn;

    k = kn; v = vn; q = qn; eta = etan;
    kn = kn2; vn = vn2; qn = qn2; etan = etan2;
    base += BD;
  }
}

// ---------------- out projection: z = H @ Wo + bo ----------------
__global__ __launch_bounds__(256) void outproj_kernel(
    const float* __restrict__ H, const float* __restrict__ Wo,
    const float* __restrict__ bo, float* __restrict__ out) {
  __shared__ __align__(16) float ht[16 * BD];  // 4 KB
  const int tid = threadIdx.x;
  const size_t row0 = (size_t)blockIdx.x * 16;
  ((float4*)ht)[tid] = ((const float4*)(H + row0 * BD))[tid];
  __syncthreads();
  float acc0[16], acc1[16];
#pragma unroll
  for (int r = 0; r < 16; r++) { acc0[r] = 0.f; acc1[r] = 0.f; }
  for (int kk = 0; kk < BD; kk++) {
    float w0 = Wo[kk * D + tid];
    float w1 = Wo[kk * D + tid + 256];
#pragma unroll
    for (int r = 0; r < 16; r++) {
      float hv = ht[r * BD + kk];
      acc0[r] += hv * w0;
      acc1[r] += hv * w1;
    }
  }
  float b0 = bo[tid], b1 = bo[tid + 256];
#pragma unroll
  for (int r = 0; r < 16; r++) {
    out[(row0 + r) * D + tid] = acc0[r] + b0;
    out[(row0 + r) * D + tid + 256] = acc1[r] + b1;
  }
}

extern "C" void kernel_launch(void* const* d_in, const int* in_sizes, int n_in,
                              void* d_out, int out_size, void* d_ws,
                              size_t ws_size, hipStream_t stream) {
  (void)in_sizes; (void)n_in; (void)out_size; (void)ws_size;
  const float* x    = (const float*)d_in[0];
  const float* Wk   = (const float*)d_in[1];
  const float* bk   = (const float*)d_in[2];
  const float* Wv   = (const float*)d_in[3];
  const float* bv   = (const float*)d_in[4];
  const float* Wq   = (const float*)d_in[5];
  const float* bq   = (const float*)d_in[6];
  const float* Wo   = (const float*)d_in[7];
  const float* bo   = (const float*)d_in[8];
  const float* ln_g = (const float*)d_in[9];
  const float* ln_b = (const float*)d_in[10];
  const float* lr_w = (const float*)d_in[11];
  const float* lr_b = (const float*)d_in[12];
  const float* W0   = (const float*)d_in[13];

  float* ws  = (float*)d_ws;
  float* Kb  = ws + OFF_K;
  float* Vb  = ws + OFF_V;
  float* Qb  = ws + OFF_Q;
  float* ETA = ws + OFF_ETA;
  float* Hb  = ws + OFF_H;
  float* out = (float*)d_out;

  proj_kernel<<<BT / 16, 256, 0, stream>>>(x, Wk, bk, Wv, bv, Wq, bq, Kb, Vb, Qb);
  eta_kernel<<<BT / 4, 256, 0, stream>>>(x, lr_w, lr_b, ETA);
  ttt_seq_kernel<<<NB, 64, 0, stream>>>(Kb, Vb, Qb, ETA, W0, ln_g, ln_b, Hb);
  outproj_kernel<<<BT / 16, 256, 0, stream>>>(Hb, Wo, bo, out);
}

// Round 4
// 2699.460 us; speedup vs baseline: 1.1654x; 1.1654x over previous
//
#include <hip/hip_runtime.h>
#include <math.h>

#define NB 16
#define T  2048
#define D  512
#define BD 64
#define BT (NB*T)  // 32768

// workspace layout (float offsets)
#define OFF_K   0
#define OFF_V   (BT*BD)
#define OFF_Q   (2*BT*BD)
#define OFF_ETA (3*BT*BD)
#define OFF_H   (3*BT*BD + BT)
// total floats = 4*BT*BD + BT = 8,421,376  (~33.7 MB)

// ---------------- DPP full-wave sum, result broadcast to all lanes ----------
__device__ __forceinline__ float wave_allsum(float x) {
  x += __int_as_float(__builtin_amdgcn_update_dpp(
      0, __float_as_int(x), 0x111, 0xf, 0xf, true));   // row_shr:1
  x += __int_as_float(__builtin_amdgcn_update_dpp(
      0, __float_as_int(x), 0x112, 0xf, 0xf, true));   // row_shr:2
  x += __int_as_float(__builtin_amdgcn_update_dpp(
      0, __float_as_int(x), 0x114, 0xf, 0xf, true));   // row_shr:4
  x += __int_as_float(__builtin_amdgcn_update_dpp(
      0, __float_as_int(x), 0x118, 0xf, 0xf, true));   // row_shr:8
  x += __int_as_float(__builtin_amdgcn_update_dpp(
      0, __float_as_int(x), 0x142, 0xa, 0xf, false));  // row_bcast:15 -> rows 1,3
  x += __int_as_float(__builtin_amdgcn_update_dpp(
      0, __float_as_int(x), 0x143, 0xc, 0xf, false));  // row_bcast:31 -> rows 2,3
  return __int_as_float(__builtin_amdgcn_readlane(__float_as_int(x), 63));
}

// ---------------- projection: K,V,Q = x @ W{k,v,q} + b ----------------
__device__ __forceinline__ void do_proj(const float* __restrict__ W,
                                        const float* __restrict__ bias,
                                        float* __restrict__ Out,
                                        const float* xs, int col, int rg,
                                        size_t row0) {
  float a0 = 0.f, a1 = 0.f, a2 = 0.f, a3 = 0.f;
  for (int d = 0; d < D; d += 4) {
    float w0 = W[(d + 0) * BD + col];
    float w1 = W[(d + 1) * BD + col];
    float w2 = W[(d + 2) * BD + col];
    float w3 = W[(d + 3) * BD + col];
    const float* xb = xs + (rg * 4) * D + d;
    float4 x0 = *(const float4*)(xb);
    float4 x1 = *(const float4*)(xb + D);
    float4 x2 = *(const float4*)(xb + 2 * D);
    float4 x3 = *(const float4*)(xb + 3 * D);
    a0 += x0.x * w0 + x0.y * w1 + x0.z * w2 + x0.w * w3;
    a1 += x1.x * w0 + x1.y * w1 + x1.z * w2 + x1.w * w3;
    a2 += x2.x * w0 + x2.y * w1 + x2.z * w2 + x2.w * w3;
    a3 += x3.x * w0 + x3.y * w1 + x3.z * w2 + x3.w * w3;
  }
  float bb = bias[col];
  Out[(row0 + rg * 4 + 0) * BD + col] = a0 + bb;
  Out[(row0 + rg * 4 + 1) * BD + col] = a1 + bb;
  Out[(row0 + rg * 4 + 2) * BD + col] = a2 + bb;
  Out[(row0 + rg * 4 + 3) * BD + col] = a3 + bb;
}

__global__ __launch_bounds__(256) void proj_kernel(
    const float* __restrict__ x,
    const float* __restrict__ Wk, const float* __restrict__ bk,
    const float* __restrict__ Wv, const float* __restrict__ bv,
    const float* __restrict__ Wq, const float* __restrict__ bq,
    float* __restrict__ Kout, float* __restrict__ Vout,
    float* __restrict__ Qout) {
  __shared__ __align__(16) float xs[16 * D];  // 32 KB
  const int tid = threadIdx.x;
  const size_t row0 = (size_t)blockIdx.x * 16;
  const float4* xg = (const float4*)(x + row0 * D);
  float4* xs4 = (float4*)xs;
#pragma unroll
  for (int i = 0; i < 8; i++) xs4[i * 256 + tid] = xg[i * 256 + tid];
  __syncthreads();
  const int col = tid & 63;
  const int rg = tid >> 6;  // 4 row-groups of 4 rows
  do_proj(Wk, bk, Kout, xs, col, rg, row0);
  do_proj(Wv, bv, Vout, xs, col, rg, row0);
  do_proj(Wq, bq, Qout, xs, col, rg, row0);
}

// ---------------- eta = sigmoid(x . lr_w + lr_b) ----------------
__global__ __launch_bounds__(256) void eta_kernel(const float* __restrict__ x,
                                                  const float* __restrict__ lr_w,
                                                  const float* __restrict__ lr_b,
                                                  float* __restrict__ eta) {
  const int tid = threadIdx.x;
  const int lane = tid & 63;
  const int wv = tid >> 6;
  const size_t r = (size_t)blockIdx.x * 4 + wv;  // one wave per row
  const float* xr = x + r * D + lane * 8;
  float4 a = *(const float4*)xr;
  float4 b = *(const float4*)(xr + 4);
  const float* lw = lr_w + lane * 8;
  float4 la = *(const float4*)lw;
  float4 lb = *(const float4*)(lw + 4);
  float p = a.x * la.x + a.y * la.y + a.z * la.z + a.w * la.w +
            b.x * lb.x + b.y * lb.y + b.z * lb.z + b.w * lb.w;
#pragma unroll
  for (int m = 32; m > 0; m >>= 1) p += __shfl_xor(p, m, 64);
  if (lane == 0) eta[r] = 1.0f / (1.0f + expf(-(p + lr_b[0])));
}

// ---------------- sequential TTT scan: one wave per batch element ----------
// Single wave per block, no barriers. __launch_bounds__(64,1): min 1 wave/EU
// -> 512-VGPR budget so w[64] + kk/qq[32 float4] stay register-resident.
// 4x-unrolled software pipeline, prefetch distance 4, no register rotation:
// stage j is reloaded by body j for t+4, consumed 4 iterations later.
__global__ __launch_bounds__(64, 1)
void ttt_seq_kernel(
    const float* __restrict__ Kin, const float* __restrict__ Vin,
    const float* __restrict__ Qin, const float* __restrict__ eta_in,
    const float* __restrict__ W0, const float* __restrict__ ln_g,
    const float* __restrict__ ln_b, float* __restrict__ Hout) {
  __shared__ __align__(16) float4 lk4[2][16];
  __shared__ __align__(16) float4 lq4[2][16];
  const int lane = threadIdx.x;
  const int b = blockIdx.x;

  // lane o holds W row o in registers
  float w[64];
  const float4* w04 = (const float4*)(W0 + (size_t)lane * BD);
#pragma unroll
  for (int i = 0; i < 16; i++) {
    float4 t4 = w04[i];
    w[4 * i] = t4.x; w[4 * i + 1] = t4.y; w[4 * i + 2] = t4.z; w[4 * i + 3] = t4.w;
  }
  const float g = ln_g[lane];
  const float bet = ln_b[lane];
  const float a = g * g;
  const float A2 = wave_allsum(a);  // sum of g^2 (constant over the scan)

  size_t base = (size_t)b * T * BD;
  size_t ebase = (size_t)b * T;

  // pipeline stages: pk[j] holds k for iteration t with t%4==j
  float pk[4], pv[4], pq[4], pe[4];
#pragma unroll
  for (int j = 0; j < 4; j++) {
    pk[j] = Kin[base + j * BD + lane];
    pv[j] = Vin[base + j * BD + lane];
    pq[j] = Qin[base + j * BD + lane];
    pe[j] = eta_in[ebase + j];
  }
  // stage t=0 broadcast buffers
  ((float*)lk4[0])[lane] = pk[0];
  ((float*)lq4[0])[lane] = pq[0];

  for (int tb = 0; tb < T; tb += 4, base += 4 * BD) {
#pragma unroll
    for (int j = 0; j < 4; j++) {
      const int buf = j & 1;
      const int nbuf = buf ^ 1;
      const int jn = (j + 1) & 3;

      // consume this stage's per-lane values, then reload it for t+4
      float kcur = pk[j], vcur = pv[j], qcur = pq[j], ecur = pe[j];
      pk[j] = Kin[base + (j + 4) * BD + lane];
      pv[j] = Vin[base + (j + 4) * BD + lane];
      pq[j] = Qin[base + (j + 4) * BD + lane];
      pe[j] = eta_in[ebase + tb + j + 4];

      // stage t+1's broadcast buffers early (k_{t+1} resident in pk[jn],
      // loaded >=3 bodies ago -> no vmcnt stall here)
      ((float*)lk4[nbuf])[lane] = pk[jn];
      ((float*)lq4[nbuf])[lane] = pq[jn];

      // pull broadcast k/q for THIS step into registers (written last body)
      float4 kk[16], qq[16];
#pragma unroll
      for (int i = 0; i < 16; i++) { kk[i] = lk4[buf][i]; qq[i] = lq4[buf][i]; }

      // u = k @ W^T  and  p = q @ W_old^T   (lane o computes row o)
      float u0 = 0.f, u1 = 0.f, u2a = 0.f, u3 = 0.f;
      float p0 = 0.f, p1 = 0.f, p2 = 0.f, p3 = 0.f;
#pragma unroll
      for (int i = 0; i < 16; i++) {
        u0 += kk[i].x * w[4 * i];      p0 += qq[i].x * w[4 * i];
        u1 += kk[i].y * w[4 * i + 1];  p1 += qq[i].y * w[4 * i + 1];
        u2a += kk[i].z * w[4 * i + 2]; p2 += qq[i].z * w[4 * i + 2];
        u3 += kk[i].w * w[4 * i + 3];  p3 += qq[i].w * w[4 * i + 3];
      }
      float u = (u0 + u1) + (u2a + u3);
      float p = (p0 + p1) + (p2 + p3);

      // ---- single merged reduction phase (7 interleaved DPP sums) ----
      float c = g * (kcur + bet - vcur);
      float Su   = wave_allsum(u);
      float Suu  = wave_allsum(u * u);
      float Sau  = wave_allsum(a * u);
      float Sauu = wave_allsum(a * u * u);
      float Sc   = wave_allsum(c);
      float Scu  = wave_allsum(c * u);
      float Qk   = wave_allsum(qcur * kcur);

      float mu = Su * (1.0f / 64);
      float var = Suu * (1.0f / 64) - mu * mu;
      float rstd = rsqrtf(var + 1e-6f);
      float xh = (u - mu) * rstd;
      float Axh   = rstd * (Sau - mu * A2);
      float Scxh  = rstd * (Scu - mu * Sc);
      float Saxh2 = rstd * rstd * (Sauu - 2.0f * mu * Sau + mu * mu * A2);
      float s1 = (2.0f / 64) * (Sc + Axh);
      float s2 = (2.0f / 64) * (Scxh + Saxh2);
      float dxh = (2.0f / 64) * (c + a * xh);
      float dldu = rstd * (dxh - s1 * (1.0f / 64) - xh * (s2 * (1.0f / 64)));
      float coef = -ecur * dldu;  // W_new row o = w + coef*k

      // u2 = q @ W_new^T = p + coef * (q.k)   (rank-1 identity)
      float u2 = p + coef * Qk;

      // W update reuses the register copies of k (no second LDS pass)
#pragma unroll
      for (int i = 0; i < 16; i++) {
        w[4 * i]     += coef * kk[i].x;
        w[4 * i + 1] += coef * kk[i].y;
        w[4 * i + 2] += coef * kk[i].z;
        w[4 * i + 3] += coef * kk[i].w;
      }

      // ---- phase 2: LN stats of u2 ----
      float Su2  = wave_allsum(u2);
      float Suu2 = wave_allsum(u2 * u2);
      float mu2 = Su2 * (1.0f / 64);
      float rstd2 = rsqrtf(Suu2 * (1.0f / 64) - mu2 * mu2 + 1e-6f);
      float h = qcur + (u2 - mu2) * rstd2 * g + bet;
      Hout[base + j * BD + lane] = h;
    }
  }
}

// ---------------- out projection: z = H @ Wo + bo ----------------
__global__ __launch_bounds__(256) void outproj_kernel(
    const float* __restrict__ H, const float* __restrict__ Wo,
    const float* __restrict__ bo, float* __restrict__ out) {
  __shared__ __align__(16) float ht[16 * BD];  // 4 KB
  const int tid = threadIdx.x;
  const size_t row0 = (size_t)blockIdx.x * 16;
  ((float4*)ht)[tid] = ((const float4*)(H + row0 * BD))[tid];
  __syncthreads();
  float acc0[16], acc1[16];
#pragma unroll
  for (int r = 0; r < 16; r++) { acc0[r] = 0.f; acc1[r] = 0.f; }
  for (int kk = 0; kk < BD; kk++) {
    float w0 = Wo[kk * D + tid];
    float w1 = Wo[kk * D + tid + 256];
#pragma unroll
    for (int r = 0; r < 16; r++) {
      float hv = ht[r * BD + kk];
      acc0[r] += hv * w0;
      acc1[r] += hv * w1;
    }
  }
  float b0 = bo[tid], b1 = bo[tid + 256];
#pragma unroll
  for (int r = 0; r < 16; r++) {
    out[(row0 + r) * D + tid] = acc0[r] + b0;
    out[(row0 + r) * D + tid + 256] = acc1[r] + b1;
  }
}

extern "C" void kernel_launch(void* const* d_in, const int* in_sizes, int n_in,
                              void* d_out, int out_size, void* d_ws,
                              size_t ws_size, hipStream_t stream) {
  (void)in_sizes; (void)n_in; (void)out_size; (void)ws_size;
  const float* x    = (const float*)d_in[0];
  const float* Wk   = (const float*)d_in[1];
  const float* bk   = (const float*)d_in[2];
  const float* Wv   = (const float*)d_in[3];
  const float* bv   = (const float*)d_in[4];
  const float* Wq   = (const float*)d_in[5];
  const float* bq   = (const float*)d_in[6];
  const float* Wo   = (const float*)d_in[7];
  const float* bo   = (const float*)d_in[8];
  const float* ln_g = (const float*)d_in[9];
  const float* ln_b = (const float*)d_in[10];
  const float* lr_w = (const float*)d_in[11];
  const float* lr_b = (const float*)d_in[12];
  const float* W0   = (const float*)d_in[13];

  float* ws  = (float*)d_ws;
  float* Kb  = ws + OFF_K;
  float* Vb  = ws + OFF_V;
  float* Qb  = ws + OFF_Q;
  float* ETA = ws + OFF_ETA;
  float* Hb  = ws + OFF_H;
  float* out = (float*)d_out;

  proj_kernel<<<BT / 16, 256, 0, stream>>>(x, Wk, bk, Wv, bv, Wq, bq, Kb, Vb, Qb);
  eta_kernel<<<BT / 4, 256, 0, stream>>>(x, lr_w, lr_b, ETA);
  ttt_seq_kernel<<<NB, 64, 0, stream>>>(Kb, Vb, Qb, ETA, W0, ln_g, ln_b, Hb);
  outproj_kernel<<<BT / 16, 256, 0, stream>>>(Hb, Wo, bo, out);
}

// Round 5
// 2570.255 us; speedup vs baseline: 1.2240x; 1.0503x over previous
//
#include <hip/hip_runtime.h>
#include <math.h>

#define NB 16
#define T  2048
#define D  512
#define BD 64
#define BT (NB*T)  // 32768

// workspace layout (float offsets)
#define OFF_K   0
#define OFF_V   (BT*BD)
#define OFF_Q   (2*BT*BD)
#define OFF_ETA (3*BT*BD)
#define OFF_H   (3*BT*BD + BT)
// total floats = 4*BT*BD + BT = 8,421,376  (~33.7 MB)

// ---------------- DPP full-wave sum, result broadcast to all lanes ----------
__device__ __forceinline__ float wave_allsum(float x) {
  x += __int_as_float(__builtin_amdgcn_update_dpp(
      0, __float_as_int(x), 0x111, 0xf, 0xf, true));   // row_shr:1
  x += __int_as_float(__builtin_amdgcn_update_dpp(
      0, __float_as_int(x), 0x112, 0xf, 0xf, true));   // row_shr:2
  x += __int_as_float(__builtin_amdgcn_update_dpp(
      0, __float_as_int(x), 0x114, 0xf, 0xf, true));   // row_shr:4
  x += __int_as_float(__builtin_amdgcn_update_dpp(
      0, __float_as_int(x), 0x118, 0xf, 0xf, true));   // row_shr:8
  x += __int_as_float(__builtin_amdgcn_update_dpp(
      0, __float_as_int(x), 0x142, 0xa, 0xf, false));  // row_bcast:15 -> rows 1,3
  x += __int_as_float(__builtin_amdgcn_update_dpp(
      0, __float_as_int(x), 0x143, 0xc, 0xf, false));  // row_bcast:31 -> rows 2,3
  return __int_as_float(__builtin_amdgcn_readlane(__float_as_int(x), 63));
}

// ---------------- projection: K,V,Q = x @ W{k,v,q} + b ----------------
__device__ __forceinline__ void do_proj(const float* __restrict__ W,
                                        const float* __restrict__ bias,
                                        float* __restrict__ Out,
                                        const float* xs, int col, int rg,
                                        size_t row0) {
  float a0 = 0.f, a1 = 0.f, a2 = 0.f, a3 = 0.f;
  for (int d = 0; d < D; d += 4) {
    float w0 = W[(d + 0) * BD + col];
    float w1 = W[(d + 1) * BD + col];
    float w2 = W[(d + 2) * BD + col];
    float w3 = W[(d + 3) * BD + col];
    const float* xb = xs + (rg * 4) * D + d;
    float4 x0 = *(const float4*)(xb);
    float4 x1 = *(const float4*)(xb + D);
    float4 x2 = *(const float4*)(xb + 2 * D);
    float4 x3 = *(const float4*)(xb + 3 * D);
    a0 += x0.x * w0 + x0.y * w1 + x0.z * w2 + x0.w * w3;
    a1 += x1.x * w0 + x1.y * w1 + x1.z * w2 + x1.w * w3;
    a2 += x2.x * w0 + x2.y * w1 + x2.z * w2 + x2.w * w3;
    a3 += x3.x * w0 + x3.y * w1 + x3.z * w2 + x3.w * w3;
  }
  float bb = bias[col];
  Out[(row0 + rg * 4 + 0) * BD + col] = a0 + bb;
  Out[(row0 + rg * 4 + 1) * BD + col] = a1 + bb;
  Out[(row0 + rg * 4 + 2) * BD + col] = a2 + bb;
  Out[(row0 + rg * 4 + 3) * BD + col] = a3 + bb;
}

__global__ __launch_bounds__(256) void proj_kernel(
    const float* __restrict__ x,
    const float* __restrict__ Wk, const float* __restrict__ bk,
    const float* __restrict__ Wv, const float* __restrict__ bv,
    const float* __restrict__ Wq, const float* __restrict__ bq,
    float* __restrict__ Kout, float* __restrict__ Vout,
    float* __restrict__ Qout) {
  __shared__ __align__(16) float xs[16 * D];  // 32 KB
  const int tid = threadIdx.x;
  const size_t row0 = (size_t)blockIdx.x * 16;
  const float4* xg = (const float4*)(x + row0 * D);
  float4* xs4 = (float4*)xs;
#pragma unroll
  for (int i = 0; i < 8; i++) xs4[i * 256 + tid] = xg[i * 256 + tid];
  __syncthreads();
  const int col = tid & 63;
  const int rg = tid >> 6;  // 4 row-groups of 4 rows
  do_proj(Wk, bk, Kout, xs, col, rg, row0);
  do_proj(Wv, bv, Vout, xs, col, rg, row0);
  do_proj(Wq, bq, Qout, xs, col, rg, row0);
}

// ---------------- eta = sigmoid(x . lr_w + lr_b) ----------------
__global__ __launch_bounds__(256) void eta_kernel(const float* __restrict__ x,
                                                  const float* __restrict__ lr_w,
                                                  const float* __restrict__ lr_b,
                                                  float* __restrict__ eta) {
  const int tid = threadIdx.x;
  const int lane = tid & 63;
  const int wv = tid >> 6;
  const size_t r = (size_t)blockIdx.x * 4 + wv;  // one wave per row
  const float* xr = x + r * D + lane * 8;
  float4 a = *(const float4*)xr;
  float4 b = *(const float4*)(xr + 4);
  const float* lw = lr_w + lane * 8;
  float4 la = *(const float4*)lw;
  float4 lb = *(const float4*)(lw + 4);
  float p = a.x * la.x + a.y * la.y + a.z * la.z + a.w * la.w +
            b.x * lb.x + b.y * lb.y + b.z * lb.z + b.w * lb.w;
#pragma unroll
  for (int m = 32; m > 0; m >>= 1) p += __shfl_xor(p, m, 64);
  if (lane == 0) eta[r] = 1.0f / (1.0f + expf(-(p + lr_b[0])));
}

// ---------------- sequential TTT scan: one wave per batch element ----------
// Single wave per block, no barriers. Key structure (round 5):
//  * k-broadcast regs kk[16] are software-pipelined ACROSS the step boundary:
//    ds_reads for step t+1 issue late in body t (after W-update's last use of
//    k_t), covered by phase-2 + next body top. Single LDS buffer is correct
//    because one wave's DS ops execute in order.
//  * q-broadcast qq[16] is double-buffered in LDS; reads issue at body top,
//    covered by the u-matvec's issue cycles.
//  * eta: one coalesced load per 64 steps + v_readlane per step (avoids any
//    uniform-address s_load -> lgkmcnt(0) drain).
__global__ __launch_bounds__(64, 1)
void ttt_seq_kernel(
    const float* __restrict__ Kin, const float* __restrict__ Vin,
    const float* __restrict__ Qin, const float* __restrict__ eta_in,
    const float* __restrict__ W0, const float* __restrict__ ln_g,
    const float* __restrict__ ln_b, float* __restrict__ Hout) {
  __shared__ __align__(16) float lk[64];
  __shared__ __align__(16) float lq[2][64];
  const int lane = threadIdx.x;
  const int b = blockIdx.x;

  float w[64];
  const float4* w04 = (const float4*)(W0 + (size_t)lane * BD);
#pragma unroll
  for (int i = 0; i < 16; i++) {
    float4 t4 = w04[i];
    w[4 * i] = t4.x; w[4 * i + 1] = t4.y; w[4 * i + 2] = t4.z; w[4 * i + 3] = t4.w;
  }
  const float g = ln_g[lane];
  const float bet = ln_b[lane];
  const float a = g * g;
  const float A2 = wave_allsum(a);

  size_t base = (size_t)b * T * BD;
  size_t ebase = (size_t)b * T;

  // per-lane global pipeline, distance 4
  float pk[4], pv[4], pq[4];
#pragma unroll
  for (int j = 0; j < 4; j++) {
    pk[j] = Kin[base + j * BD + lane];
    pv[j] = Vin[base + j * BD + lane];
    pq[j] = Qin[base + j * BD + lane];
  }
  // eta chunks (64 steps per chunk)
  float ev  = eta_in[ebase + lane];        // chunk 0
  float evn = eta_in[ebase + 64 + lane];   // chunk 1

  // prologue: stage t=0 and preload kk (k_0), lq[0] (q_0)
  lk[lane] = pk[0];
  lq[0][lane] = pq[0];
  float4 kk[16];
  {
    const float4* lk4 = (const float4*)lk;
#pragma unroll
    for (int i = 0; i < 16; i++) kk[i] = lk4[i];
  }

  for (int c = 0; c < 32; c++) {
    // issue chunk c+2's eta load now (64 bodies of cover)
    float ev2 = eta_in[ebase + (size_t)(c + 2) * 64 + lane];

    for (int g4 = 0; g4 < 16; g4++) {
#pragma unroll
      for (int j = 0; j < 4; j++) {
        const int jn = (j + 1) & 3;
        const int pt = j & 1;        // q-buffer parity for step t
        const int ptn = pt ^ 1;
        const int i_in_chunk = (g4 << 2) + j;

        float kcur = pk[j], vcur = pv[j], qcur = pq[j];
        float ecur = __int_as_float(
            __builtin_amdgcn_readlane(__float_as_int(ev), i_in_chunk));

        // reload stage j for t+4 (off-end reads stay inside d_ws)
        pk[j] = Kin[base + 4 * BD + lane];
        pv[j] = Vin[base + 4 * BD + lane];
        pq[j] = Qin[base + 4 * BD + lane];

        // stage t+1's broadcasts (pk[jn]/pq[jn] loaded 3 bodies ago)
        lk[lane] = pk[jn];
        lq[ptn][lane] = pq[jn];

        // stream q_t broadcast: reads issue here, consumed after u-matvec
        float4 qq[16];
        {
          const float4* lq4 = (const float4*)lq[pt];
#pragma unroll
          for (int i = 0; i < 16; i++) qq[i] = lq4[i];
        }

        // u = k @ W^T (kk regs prefetched last body), then p = q @ W_old^T
        float u0 = 0.f, u1 = 0.f, u2a = 0.f, u3 = 0.f;
#pragma unroll
        for (int i = 0; i < 16; i++) {
          u0  += kk[i].x * w[4 * i];
          u1  += kk[i].y * w[4 * i + 1];
          u2a += kk[i].z * w[4 * i + 2];
          u3  += kk[i].w * w[4 * i + 3];
        }
        float p0 = 0.f, p1 = 0.f, p2 = 0.f, p3 = 0.f;
#pragma unroll
        for (int i = 0; i < 16; i++) {
          p0 += qq[i].x * w[4 * i];
          p1 += qq[i].y * w[4 * i + 1];
          p2 += qq[i].z * w[4 * i + 2];
          p3 += qq[i].w * w[4 * i + 3];
        }
        float u = (u0 + u1) + (u2a + u3);
        float p = (p0 + p1) + (p2 + p3);

        // ---- merged reduction phase (7 interleaved DPP sums) ----
        float c0 = g * (kcur + bet - vcur);
        float Su   = wave_allsum(u);
        float Suu  = wave_allsum(u * u);
        float Sau  = wave_allsum(a * u);
        float Sauu = wave_allsum(a * u * u);
        float Sc   = wave_allsum(c0);
        float Scu  = wave_allsum(c0 * u);
        float Qk   = wave_allsum(qcur * kcur);

        float mu = Su * (1.0f / 64);
        float var = Suu * (1.0f / 64) - mu * mu;
        float rstd = rsqrtf(var + 1e-6f);
        float xh = (u - mu) * rstd;
        float Axh   = rstd * (Sau - mu * A2);
        float Scxh  = rstd * (Scu - mu * Sc);
        float Saxh2 = rstd * rstd * (Sauu - 2.0f * mu * Sau + mu * mu * A2);
        float s1 = (2.0f / 64) * (Sc + Axh);
        float s2 = (2.0f / 64) * (Scxh + Saxh2);
        float dxh = (2.0f / 64) * (c0 + a * xh);
        float dldu = rstd * (dxh - s1 * (1.0f / 64) - xh * (s2 * (1.0f / 64)));
        float coef = -ecur * dldu;  // W_new row o = w + coef*k

        // u2 = q @ W_new^T = p + coef * (q.k)
        float u2 = p + coef * Qk;

        // W update: last use of kk (k_t)
#pragma unroll
        for (int i = 0; i < 16; i++) {
          w[4 * i]     += coef * kk[i].x;
          w[4 * i + 1] += coef * kk[i].y;
          w[4 * i + 2] += coef * kk[i].z;
          w[4 * i + 3] += coef * kk[i].w;
        }

        // prefetch k_{t+1} broadcast into kk for next body (in-order DS pipe:
        // these reads follow this body's top write of lk = k_{t+1})
        {
          const float4* lk4 = (const float4*)lk;
#pragma unroll
          for (int i = 0; i < 16; i++) kk[i] = lk4[i];
        }
        __builtin_amdgcn_sched_barrier(0);  // pin reads above phase 2

        // ---- phase 2: LN stats of u2 ----
        float Su2  = wave_allsum(u2);
        float Suu2 = wave_allsum(u2 * u2);
        float mu2 = Su2 * (1.0f / 64);
        float rstd2 = rsqrtf(Suu2 * (1.0f / 64) - mu2 * mu2 + 1e-6f);
        float h = qcur + (u2 - mu2) * rstd2 * g + bet;
        Hout[base + lane] = h;

        base += BD;
      }
    }
    ev = evn; evn = ev2;
  }
}

// ---------------- out projection: z = H @ Wo + bo ----------------
__global__ __launch_bounds__(256) void outproj_kernel(
    const float* __restrict__ H, const float* __restrict__ Wo,
    const float* __restrict__ bo, float* __restrict__ out) {
  __shared__ __align__(16) float ht[16 * BD];  // 4 KB
  const int tid = threadIdx.x;
  const size_t row0 = (size_t)blockIdx.x * 16;
  ((float4*)ht)[tid] = ((const float4*)(H + row0 * BD))[tid];
  __syncthreads();
  float acc0[16], acc1[16];
#pragma unroll
  for (int r = 0; r < 16; r++) { acc0[r] = 0.f; acc1[r] = 0.f; }
  for (int kk = 0; kk < BD; kk++) {
    float w0 = Wo[kk * D + tid];
    float w1 = Wo[kk * D + tid + 256];
#pragma unroll
    for (int r = 0; r < 16; r++) {
      float hv = ht[r * BD + kk];
      acc0[r] += hv * w0;
      acc1[r] += hv * w1;
    }
  }
  float b0 = bo[tid], b1 = bo[tid + 256];
#pragma unroll
  for (int r = 0; r < 16; r++) {
    out[(row0 + r) * D + tid] = acc0[r] + b0;
    out[(row0 + r) * D + tid + 256] = acc1[r] + b1;
  }
}

extern "C" void kernel_launch(void* const* d_in, const int* in_sizes, int n_in,
                              void* d_out, int out_size, void* d_ws,
                              size_t ws_size, hipStream_t stream) {
  (void)in_sizes; (void)n_in; (void)out_size; (void)ws_size;
  const float* x    = (const float*)d_in[0];
  const float* Wk   = (const float*)d_in[1];
  const float* bk   = (const float*)d_in[2];
  const float* Wv   = (const float*)d_in[3];
  const float* bv   = (const float*)d_in[4];
  const float* Wq   = (const float*)d_in[5];
  const float* bq   = (const float*)d_in[6];
  const float* Wo   = (const float*)d_in[7];
  const float* bo   = (const float*)d_in[8];
  const float* ln_g = (const float*)d_in[9];
  const float* ln_b = (const float*)d_in[10];
  const float* lr_w = (const float*)d_in[11];
  const float* lr_b = (const float*)d_in[12];
  const float* W0   = (const float*)d_in[13];

  float* ws  = (float*)d_ws;
  float* Kb  = ws + OFF_K;
  float* Vb  = ws + OFF_V;
  float* Qb  = ws + OFF_Q;
  float* ETA = ws + OFF_ETA;
  float* Hb  = ws + OFF_H;
  float* out = (float*)d_out;

  proj_kernel<<<BT / 16, 256, 0, stream>>>(x, Wk, bk, Wv, bv, Wq, bq, Kb, Vb, Qb);
  eta_kernel<<<BT / 4, 256, 0, stream>>>(x, lr_w, lr_b, ETA);
  ttt_seq_kernel<<<NB, 64, 0, stream>>>(Kb, Vb, Qb, ETA, W0, ln_g, ln_b, Hb);
  outproj_kernel<<<BT / 16, 256, 0, stream>>>(Hb, Wo, bo, out);
}